// Round 1
// baseline (858.919 us; speedup 1.0000x reference)
//
#include <hip/hip_runtime.h>
#include <hip/hip_bf16.h>
#include <stdint.h>

#define NTOK 4096
#define EMBD 1024
#define NEXP 8
#define HIDD 2048
#define NPAIR (NTOK * 2)

typedef __attribute__((ext_vector_type(8))) __bf16 bf16x8;
typedef __attribute__((ext_vector_type(4))) float f32x4;

union V16 { uint4 u; bf16x8 b; };

__device__ __forceinline__ uint16_t f2bf(float f) {
    uint32_t u = __float_as_uint(f);
    return (uint16_t)((u + 0x7FFFu + ((u >> 16) & 1u)) >> 16);
}

// ---- cast x (fp32 -> bf16), 4 elems/thread ----
__global__ __launch_bounds__(256) void cast_x_kernel(const float* __restrict__ x,
                                                     uint16_t* __restrict__ xb) {
    int i = blockIdx.x * 256 + threadIdx.x;
    float4 v = ((const float4*)x)[i];
    ushort4 o;
    o.x = f2bf(v.x); o.y = f2bf(v.y); o.z = f2bf(v.z); o.w = f2bf(v.w);
    ((ushort4*)xb)[i] = o;
}

// ---- router: one wave per token ----
__global__ __launch_bounds__(64) void router_kernel(const float* __restrict__ x,
                                                    const float* __restrict__ Wr,
                                                    const float* __restrict__ br,
                                                    int* __restrict__ counts,
                                                    int* __restrict__ pair_e,
                                                    float* __restrict__ pair_p) {
    int tok = blockIdx.x;
    int lane = threadIdx.x;
    const float* xr = x + (size_t)tok * EMBD;
    float acc[NEXP];
#pragma unroll
    for (int e = 0; e < NEXP; e++) acc[e] = 0.f;
    for (int d = lane; d < EMBD; d += 64) {
        float xv = xr[d];
#pragma unroll
        for (int e = 0; e < NEXP; e++) acc[e] += xv * Wr[d * NEXP + e];
    }
#pragma unroll
    for (int e = 0; e < NEXP; e++) {
#pragma unroll
        for (int off = 32; off > 0; off >>= 1)
            acc[e] += __shfl_down(acc[e], off, 64);
    }
    if (lane == 0) {
        float lg[NEXP];
#pragma unroll
        for (int e = 0; e < NEXP; e++) lg[e] = acc[e] + br[e];
        // top2 on logits (softmax monotonic); strict > keeps lowest index on tie (jax)
        int e0 = 0;
#pragma unroll
        for (int e = 1; e < NEXP; e++) if (lg[e] > lg[e0]) e0 = e;
        int e1 = (e0 == 0) ? 1 : 0;
#pragma unroll
        for (int e = 0; e < NEXP; e++) if (e != e0 && lg[e] > lg[e1]) e1 = e;
        float mx = lg[0];
#pragma unroll
        for (int e = 1; e < NEXP; e++) mx = fmaxf(mx, lg[e]);
        float s = 0.f, p[NEXP];
#pragma unroll
        for (int e = 0; e < NEXP; e++) { p[e] = __expf(lg[e] - mx); s += p[e]; }
        float inv = 1.f / s;
        pair_e[tok * 2 + 0] = e0; pair_p[tok * 2 + 0] = p[e0] * inv;
        pair_e[tok * 2 + 1] = e1; pair_p[tok * 2 + 1] = p[e1] * inv;
        atomicAdd(&counts[e0], 1);
        atomicAdd(&counts[e1], 1);
    }
}

__global__ void scan_kernel(const int* __restrict__ counts, int* __restrict__ offsets) {
    if (threadIdx.x == 0 && blockIdx.x == 0) {
        int s = 0;
        for (int e = 0; e < NEXP; e++) { offsets[e] = s; s += counts[e]; }
    }
}

__global__ __launch_bounds__(256) void scatter_kernel(const int* __restrict__ pair_e,
                                                      const float* __restrict__ pair_p,
                                                      const int* __restrict__ offsets,
                                                      int* __restrict__ cursors,
                                                      int* __restrict__ toklist,
                                                      float* __restrict__ problist) {
    int i = blockIdx.x * 256 + threadIdx.x;  // pair index
    int e = pair_e[i];
    int pos = offsets[e] + atomicAdd(&cursors[e], 1);
    toklist[pos] = i >> 1;
    problist[pos] = pair_p[i];
}

// ---- grouped GEMM: 64x64 tile, BK=32, 4 waves, mfma_f32_16x16x32_bf16 ----
// A: bf16 (gathered x rows for layer1, else contiguous rows offs+m)
// B: fp32 weights [NEXP][KDIM][NDIM], converted to bf16 during staging
template <int KDIM, int NDIM, bool GATHER_A, bool RELU, bool SCATTER>
__global__ __launch_bounds__(256) void gemm_kernel(
    const uint16_t* __restrict__ Abase, const float* __restrict__ Wbase,
    const float* __restrict__ bbase, uint16_t* __restrict__ Obf,
    float* __restrict__ Oscat, const int* __restrict__ counts,
    const int* __restrict__ offsets, const int* __restrict__ toklist,
    const float* __restrict__ problist) {
    int e = blockIdx.z;
    int n_e = counts[e];
    int m0 = blockIdx.y * 64;
    if (m0 >= n_e) return;
    int n0 = blockIdx.x * 64;
    int offs = offsets[e];
    const float* W = Wbase + (size_t)e * KDIM * NDIM;
    const float* bias = bbase + (size_t)e * NDIM;

    __shared__ uint16_t As[64][40];  // [m][k], stride 40 breaks bank conflicts
    __shared__ uint16_t Bs[64][40];  // [n][k]

    int tid = threadIdx.x;
    int lane = tid & 63;
    int wave = tid >> 6;
    int wm = (wave >> 1) * 32, wn = (wave & 1) * 32;
    int qd = lane >> 4;
    int l16 = lane & 15;

    // A staging: thread -> (row, 8-elem k-segment)
    int ar = tid >> 2;
    int aseg = (tid & 3) * 8;
    bool avalid = (m0 + ar) < n_e;
    int arow;
    if (GATHER_A) {
        int p = offs + m0 + (avalid ? ar : 0);
        arow = toklist[p];
    } else {
        arow = offs + m0 + (avalid ? ar : 0);
    }
    const uint16_t* Arow = Abase + (size_t)arow * KDIM + aseg;

    // B staging: thread -> (n, 8 k's)
    int bn = tid & 63;
    int bkg = (tid >> 6) * 8;

    f32x4 acc[2][2];
    f32x4 zero = {0.f, 0.f, 0.f, 0.f};
    acc[0][0] = zero; acc[0][1] = zero; acc[1][0] = zero; acc[1][1] = zero;

    for (int kb = 0; kb < KDIM; kb += 32) {
        uint4 av = {0u, 0u, 0u, 0u};
        if (avalid) av = *(const uint4*)(Arow + kb);
        *(uint4*)(&As[ar][aseg]) = av;
#pragma unroll
        for (int kk = 0; kk < 8; kk++) {
            float bv = W[(size_t)(kb + bkg + kk) * NDIM + n0 + bn];
            Bs[bn][bkg + kk] = f2bf(bv);
        }
        __syncthreads();
        V16 afr[2], bfr[2];
#pragma unroll
        for (int t = 0; t < 2; t++) {
            afr[t].u = *(const uint4*)(&As[wm + t * 16 + l16][qd * 8]);
            bfr[t].u = *(const uint4*)(&Bs[wn + t * 16 + l16][qd * 8]);
        }
#pragma unroll
        for (int ti = 0; ti < 2; ti++)
#pragma unroll
            for (int tj = 0; tj < 2; tj++)
                acc[ti][tj] = __builtin_amdgcn_mfma_f32_16x16x32_bf16(
                    afr[ti].b, bfr[tj].b, acc[ti][tj], 0, 0, 0);
        __syncthreads();
    }

    // epilogue: C/D layout col=lane&15, row=quad*4+reg
#pragma unroll
    for (int ti = 0; ti < 2; ti++) {
        int rbase = m0 + wm + ti * 16 + qd * 4;
#pragma unroll
        for (int tj = 0; tj < 2; tj++) {
            int col = n0 + wn + tj * 16 + l16;
            float bv = bias[col];
#pragma unroll
            for (int r = 0; r < 4; r++) {
                int row = rbase + r;
                if (row < n_e) {
                    float v = acc[ti][tj][r] + bv;
                    if (RELU) v = fmaxf(v, 0.f);
                    if (SCATTER) {
                        int p = offs + row;
                        int tok = toklist[p];
                        float pr = problist[p];
                        atomicAdd(&Oscat[(size_t)tok * NDIM + col], pr * v);
                    } else {
                        Obf[(size_t)(offs + row) * NDIM + col] = f2bf(v);
                    }
                }
            }
        }
    }
}

extern "C" void kernel_launch(void* const* d_in, const int* in_sizes, int n_in,
                              void* d_out, int out_size, void* d_ws, size_t ws_size,
                              hipStream_t stream) {
    const float* x  = (const float*)d_in[0];
    const float* Wr = (const float*)d_in[1];
    const float* br = (const float*)d_in[2];
    const float* W1 = (const float*)d_in[3];
    const float* b1 = (const float*)d_in[4];
    const float* Wg = (const float*)d_in[5];
    const float* bg = (const float*)d_in[6];
    const float* W2 = (const float*)d_in[7];
    const float* b2 = (const float*)d_in[8];
    float* out = (float*)d_out;

    char* ws = (char*)d_ws;
    uint16_t* xb = (uint16_t*)ws;                       //  8 MB: x bf16
    uint16_t* h  = (uint16_t*)(ws + (8ull << 20));      // 32 MB: layer1 out
    uint16_t* g  = (uint16_t*)(ws + (40ull << 20));     // 32 MB: layer2 out
    int* meta = (int*)(ws + (72ull << 20));
    int*   counts   = meta;                 // 8
    int*   offsets  = meta + 8;             // 8
    int*   cursors  = meta + 16;            // 8
    int*   pair_e   = meta + 24;            // 8192
    int*   toklist  = meta + 24 + NPAIR;    // 8192
    float* pair_p   = (float*)(meta + 24 + 2 * NPAIR);  // 8192
    float* problist = (float*)(meta + 24 + 3 * NPAIR);  // 8192

    hipMemsetAsync(out, 0, (size_t)NTOK * EMBD * sizeof(float), stream);
    hipMemsetAsync(counts, 0, 24 * sizeof(int), stream);

    cast_x_kernel<<<(NTOK * EMBD) / (256 * 4), 256, 0, stream>>>(x, xb);
    router_kernel<<<NTOK, 64, 0, stream>>>(x, Wr, br, counts, pair_e, pair_p);
    scan_kernel<<<1, 64, 0, stream>>>(counts, offsets);
    scatter_kernel<<<NPAIR / 256, 256, 0, stream>>>(pair_e, pair_p, offsets, cursors,
                                                    toklist, problist);
    // layer1: [n_e,1024] x [1024,2048]
    gemm_kernel<EMBD, HIDD, true, false, false>
        <<<dim3(HIDD / 64, NTOK / 64, NEXP), 256, 0, stream>>>(
            xb, W1, b1, h, nullptr, counts, offsets, toklist, problist);
    // layer2: [n_e,2048] x [2048,2048], relu
    gemm_kernel<HIDD, HIDD, false, true, false>
        <<<dim3(HIDD / 64, NTOK / 64, NEXP), 256, 0, stream>>>(
            h, Wg, bg, g, nullptr, counts, offsets, toklist, problist);
    // layer3: [n_e,2048] x [2048,1024], scatter-add gate*y
    gemm_kernel<HIDD, EMBD, false, false, true>
        <<<dim3(EMBD / 64, NTOK / 64, NEXP), 256, 0, stream>>>(
            g, W2, b2, nullptr, out, counts, offsets, toklist, problist);
}

// Round 2
// 765.851 us; speedup vs baseline: 1.1215x; 1.1215x over previous
//
#include <hip/hip_runtime.h>
#include <hip/hip_bf16.h>
#include <stdint.h>

#define NTOK 4096
#define EMBD 1024
#define NEXP 8
#define HIDD 2048
#define NPAIR (NTOK * 2)

typedef __attribute__((ext_vector_type(8))) __bf16 bf16x8;
typedef __attribute__((ext_vector_type(4))) float f32x4;

union V16 { uint4 u; bf16x8 b; };

__device__ __forceinline__ uint16_t f2bf(float f) {
    uint32_t u = __float_as_uint(f);
    return (uint16_t)((u + 0x7FFFu + ((u >> 16) & 1u)) >> 16);
}
__device__ __forceinline__ float bf2f(uint16_t u) {
    return __uint_as_float(((uint32_t)u) << 16);
}
__device__ __forceinline__ void gl_lds16(const uint16_t* g, uint16_t* l) {
    __builtin_amdgcn_global_load_lds(
        (const __attribute__((address_space(1))) void*)g,
        (__attribute__((address_space(3))) void*)l, 16, 0, 0);
}

// ---- cast x (fp32 -> bf16), 4 elems/thread ----
__global__ __launch_bounds__(256) void cast_x_kernel(const float* __restrict__ x,
                                                     uint16_t* __restrict__ xb) {
    int i = blockIdx.x * 256 + threadIdx.x;
    float4 v = ((const float4*)x)[i];
    ushort4 o;
    o.x = f2bf(v.x); o.y = f2bf(v.y); o.z = f2bf(v.z); o.w = f2bf(v.w);
    ((ushort4*)xb)[i] = o;
}

// ---- transpose-cast weights: src [E][K][N] fp32 -> dst [E][N][K] bf16 ----
__global__ __launch_bounds__(256) void transcast_kernel(const float* __restrict__ src,
                                                        uint16_t* __restrict__ dst,
                                                        int K, int N) {
    int e = blockIdx.z;
    int k0 = blockIdx.y * 64, n0 = blockIdx.x * 64;
    __shared__ uint16_t tile[64][65];
    const float* S = src + ((size_t)e * K + k0) * N + n0;
    uint16_t* D = dst + ((size_t)e * N + n0) * K + k0;
    int tx = threadIdx.x & 63, ty = threadIdx.x >> 6;
#pragma unroll
    for (int kk = ty; kk < 64; kk += 4)
        tile[kk][tx] = f2bf(S[(size_t)kk * N + tx]);
    __syncthreads();
    int tx2 = threadIdx.x & 31, tyw = threadIdx.x >> 5;
#pragma unroll
    for (int nn = tyw; nn < 64; nn += 8) {
        uint32_t lo = tile[2 * tx2][nn], hi = tile[2 * tx2 + 1][nn];
        *(uint32_t*)&D[(size_t)nn * K + 2 * tx2] = lo | (hi << 16);
    }
}

// ---- router: one wave per token ----
__global__ __launch_bounds__(64) void router_kernel(const float* __restrict__ x,
                                                    const float* __restrict__ Wr,
                                                    const float* __restrict__ br,
                                                    int* __restrict__ counts,
                                                    int* __restrict__ pair_e,
                                                    float* __restrict__ pair_p) {
    int tok = blockIdx.x;
    int lane = threadIdx.x;
    const float* xr = x + (size_t)tok * EMBD;
    float acc[NEXP];
#pragma unroll
    for (int e = 0; e < NEXP; e++) acc[e] = 0.f;
    for (int d = lane; d < EMBD; d += 64) {
        float xv = xr[d];
#pragma unroll
        for (int e = 0; e < NEXP; e++) acc[e] += xv * Wr[d * NEXP + e];
    }
#pragma unroll
    for (int e = 0; e < NEXP; e++) {
#pragma unroll
        for (int off = 32; off > 0; off >>= 1)
            acc[e] += __shfl_down(acc[e], off, 64);
    }
    if (lane == 0) {
        float lg[NEXP];
#pragma unroll
        for (int e = 0; e < NEXP; e++) lg[e] = acc[e] + br[e];
        int e0 = 0;
#pragma unroll
        for (int e = 1; e < NEXP; e++) if (lg[e] > lg[e0]) e0 = e;
        int e1 = (e0 == 0) ? 1 : 0;
#pragma unroll
        for (int e = 0; e < NEXP; e++) if (e != e0 && lg[e] > lg[e1]) e1 = e;
        float mx = lg[0];
#pragma unroll
        for (int e = 1; e < NEXP; e++) mx = fmaxf(mx, lg[e]);
        float s = 0.f, p[NEXP];
#pragma unroll
        for (int e = 0; e < NEXP; e++) { p[e] = __expf(lg[e] - mx); s += p[e]; }
        float inv = 1.f / s;
        pair_e[tok * 2 + 0] = e0; pair_p[tok * 2 + 0] = p[e0] * inv;
        pair_e[tok * 2 + 1] = e1; pair_p[tok * 2 + 1] = p[e1] * inv;
        atomicAdd(&counts[e0], 1);
        atomicAdd(&counts[e1], 1);
    }
}

__global__ void scan_kernel(const int* __restrict__ counts, int* __restrict__ offsets) {
    if (threadIdx.x == 0 && blockIdx.x == 0) {
        int s = 0;
        for (int e = 0; e < NEXP; e++) { offsets[e] = s; s += counts[e]; }
    }
}

__global__ __launch_bounds__(256) void scatter_kernel(const int* __restrict__ pair_e,
                                                      const int* __restrict__ offsets,
                                                      int* __restrict__ cursors,
                                                      int* __restrict__ toklist,
                                                      int* __restrict__ posmap) {
    int i = blockIdx.x * 256 + threadIdx.x;  // pair index
    int e = pair_e[i];
    int pos = offsets[e] + atomicAdd(&cursors[e], 1);
    toklist[pos] = i >> 1;
    posmap[i] = pos;
}

// ---- grouped GEMM, m97 structure: 128x128 tile, BK=32, 4 waves, 4x4 MFMA/wave
// A: bf16 [rows][KDIM] (gathered token rows for layer1, else contiguous offs+m)
// Bt: bf16 [E][NDIM][KDIM] (pre-transposed weights)
// Out: bf16 [rows][NDIM] at offs+row
template <int KDIM, int NDIM, bool GATHER_A, bool RELU>
__global__ __launch_bounds__(256) void gemm_kernel(
    const uint16_t* __restrict__ Abase, const uint16_t* __restrict__ Btbase,
    const float* __restrict__ bbase, uint16_t* __restrict__ Out,
    const int* __restrict__ counts, const int* __restrict__ offsets,
    const int* __restrict__ toklist) {
    int e = blockIdx.z;
    int n_e = counts[e];
    int m0 = blockIdx.y * 128;
    if (m0 >= n_e) return;
    int n0 = blockIdx.x * 128;
    int offs = offsets[e];
    const uint16_t* Bt = Btbase + (size_t)e * NDIM * KDIM;

    // no padding: global_load_lds scatters lane i at uniform base + i*16B.
    // XOR swizzle: LDS slot s of row r holds global k-segment s ^ ((r>>1)&3)
    // -> ds_read_b128 fragment reads are bank-uniform (max 2-way, free).
    __shared__ uint16_t As[128 * 32];
    __shared__ uint16_t Bs[128 * 32];

    int tid = threadIdx.x;
    int lane = tid & 63;
    int wave = tid >> 6;

    // staging: thread -> (row sr in pass, 8-elem segment slot ss)
    int sr = tid >> 2;
    int ss = tid & 3;
    const uint16_t* arp[2];
    const uint16_t* brp[2];
#pragma unroll
    for (int p = 0; p < 2; p++) {
        int r = p * 64 + sr;
        int gs = ss ^ ((r >> 1) & 3);
        int grow;
        if (GATHER_A) {
            int idx = m0 + r;
            if (idx >= n_e) idx = 0;
            grow = toklist[offs + idx];
        } else {
            grow = offs + m0 + r;  // rows >= n_e read garbage; never stored
        }
        arp[p] = Abase + (size_t)grow * KDIM + gs * 8;
        brp[p] = Bt + (size_t)(n0 + r) * KDIM + gs * 8;
    }
    // wave-uniform LDS bases (lane lands at base + lane*16B)
    uint16_t* alds[2] = { &As[wave * 512], &As[2048 + wave * 512] };
    uint16_t* blds[2] = { &Bs[wave * 512], &Bs[2048 + wave * 512] };

    // fragment read addresses (fixed across K-blocks)
    int wm = (wave >> 1) * 64;
    int wn = (wave & 1) * 64;
    int l16 = lane & 15, qd = lane >> 4;
    const uint16_t* afp[4];
    const uint16_t* bfp[4];
#pragma unroll
    for (int t = 0; t < 4; t++) {
        int ar = wm + t * 16 + l16;
        afp[t] = &As[ar * 32 + (qd ^ ((ar >> 1) & 3)) * 8];
        int br = wn + t * 16 + l16;
        bfp[t] = &Bs[br * 32 + (qd ^ ((br >> 1) & 3)) * 8];
    }

    f32x4 acc[4][4];
    f32x4 zero = {0.f, 0.f, 0.f, 0.f};
#pragma unroll
    for (int i = 0; i < 4; i++)
#pragma unroll
        for (int j = 0; j < 4; j++) acc[i][j] = zero;

    for (int kb = 0; kb < KDIM; kb += 32) {
#pragma unroll
        for (int p = 0; p < 2; p++) {
            gl_lds16(arp[p] + kb, alds[p]);
            gl_lds16(brp[p] + kb, blds[p]);
        }
        __syncthreads();
        V16 af[4], bf[4];
#pragma unroll
        for (int t = 0; t < 4; t++) {
            af[t].u = *(const uint4*)(afp[t]);
            bf[t].u = *(const uint4*)(bfp[t]);
        }
#pragma unroll
        for (int i = 0; i < 4; i++)
#pragma unroll
            for (int j = 0; j < 4; j++)
                acc[i][j] = __builtin_amdgcn_mfma_f32_16x16x32_bf16(
                    af[i].b, bf[j].b, acc[i][j], 0, 0, 0);
        __syncthreads();
    }

    // epilogue: C/D layout col=lane&15, row=(lane>>4)*4+reg
    const float* bias = bbase + (size_t)e * NDIM;
    int mrem = n_e - m0;
#pragma unroll
    for (int i = 0; i < 4; i++) {
        int rb = wm + i * 16 + qd * 4;
#pragma unroll
        for (int j = 0; j < 4; j++) {
            int col = n0 + wn + j * 16 + l16;
            float bv = bias[col];
#pragma unroll
            for (int r = 0; r < 4; r++) {
                int lr = rb + r;
                if (lr < mrem) {
                    float v = acc[i][j][r] + bv;
                    if (RELU) v = fmaxf(v, 0.f);
                    Out[(size_t)(offs + m0 + lr) * NDIM + col] = f2bf(v);
                }
            }
        }
    }
}

// ---- combine: out[t] = p0*y[pos0] + p1*y[pos1] ----
__global__ __launch_bounds__(256) void combine_kernel(const uint16_t* __restrict__ y,
                                                      const int* __restrict__ posmap,
                                                      const float* __restrict__ pair_p,
                                                      float* __restrict__ out) {
    int t = blockIdx.x;
    int d4 = threadIdx.x;  // 4 elems each
    int p0 = posmap[t * 2], p1 = posmap[t * 2 + 1];
    float w0 = pair_p[t * 2], w1 = pair_p[t * 2 + 1];
    ushort4 a = ((const ushort4*)(y + (size_t)p0 * EMBD))[d4];
    ushort4 b = ((const ushort4*)(y + (size_t)p1 * EMBD))[d4];
    float4 o;
    o.x = w0 * bf2f(a.x) + w1 * bf2f(b.x);
    o.y = w0 * bf2f(a.y) + w1 * bf2f(b.y);
    o.z = w0 * bf2f(a.z) + w1 * bf2f(b.z);
    o.w = w0 * bf2f(a.w) + w1 * bf2f(b.w);
    ((float4*)(out + (size_t)t * EMBD))[d4] = o;
}

extern "C" void kernel_launch(void* const* d_in, const int* in_sizes, int n_in,
                              void* d_out, int out_size, void* d_ws, size_t ws_size,
                              hipStream_t stream) {
    const float* x  = (const float*)d_in[0];
    const float* Wr = (const float*)d_in[1];
    const float* br = (const float*)d_in[2];
    const float* W1 = (const float*)d_in[3];
    const float* b1 = (const float*)d_in[4];
    const float* Wg = (const float*)d_in[5];
    const float* bg = (const float*)d_in[6];
    const float* W2 = (const float*)d_in[7];
    const float* b2 = (const float*)d_in[8];
    float* out = (float*)d_out;

    char* ws = (char*)d_ws;
    uint16_t* xb  = (uint16_t*)ws;                    //  8 MB
    uint16_t* h   = (uint16_t*)(ws + (8ull << 20));   // 32 MB; y aliases (h dead at L3)
    uint16_t* yb  = h;
    uint16_t* W1t = (uint16_t*)(ws + (40ull << 20));  // 32 MB; g aliases (W1t dead at L2)
    uint16_t* g   = W1t;
    uint16_t* Wgt = (uint16_t*)(ws + (72ull << 20));  // 64 MB
    uint16_t* W2t = (uint16_t*)(ws + (136ull << 20)); // 32 MB
    int* meta = (int*)(ws + (168ull << 20));
    int*   counts  = meta;                    // 8
    int*   offsets = meta + 8;                // 8
    int*   cursors = meta + 16;               // 8
    int*   pair_e  = meta + 24;               // NPAIR
    int*   toklist = meta + 24 + NPAIR;       // NPAIR
    int*   posmap  = meta + 24 + 2 * NPAIR;   // NPAIR
    float* pair_p  = (float*)(meta + 24 + 3 * NPAIR);  // NPAIR

    hipMemsetAsync(counts, 0, 24 * sizeof(int), stream);

    cast_x_kernel<<<(NTOK * EMBD) / (256 * 4), 256, 0, stream>>>(x, xb);
    transcast_kernel<<<dim3(HIDD / 64, EMBD / 64, NEXP), 256, 0, stream>>>(W1, W1t, EMBD, HIDD);
    transcast_kernel<<<dim3(HIDD / 64, HIDD / 64, NEXP), 256, 0, stream>>>(Wg, Wgt, HIDD, HIDD);
    transcast_kernel<<<dim3(EMBD / 64, HIDD / 64, NEXP), 256, 0, stream>>>(W2, W2t, HIDD, EMBD);
    router_kernel<<<NTOK, 64, 0, stream>>>(x, Wr, br, counts, pair_e, pair_p);
    scan_kernel<<<1, 64, 0, stream>>>(counts, offsets);
    scatter_kernel<<<NPAIR / 256, 256, 0, stream>>>(pair_e, offsets, cursors, toklist, posmap);

    // layer1: [n_e,1024] x [1024,2048]
    gemm_kernel<EMBD, HIDD, true, false>
        <<<dim3(HIDD / 128, NTOK / 128, NEXP), 256, 0, stream>>>(
            xb, W1t, b1, h, counts, offsets, toklist);
    // layer2: relu([n_e,2048] x [2048,2048])
    gemm_kernel<HIDD, HIDD, false, true>
        <<<dim3(HIDD / 128, NTOK / 128, NEXP), 256, 0, stream>>>(
            h, Wgt, bg, g, counts, offsets, toklist);
    // layer3: [n_e,2048] x [2048,1024]
    gemm_kernel<HIDD, EMBD, false, false>
        <<<dim3(EMBD / 128, NTOK / 128, NEXP), 256, 0, stream>>>(
            g, W2t, b2, yb, counts, offsets, toklist);
    combine_kernel<<<NTOK, 256, 0, stream>>>(yb, posmap, pair_p, out);
}

// Round 3
// 737.145 us; speedup vs baseline: 1.1652x; 1.0389x over previous
//
#include <hip/hip_runtime.h>
#include <hip/hip_bf16.h>
#include <stdint.h>

#define NTOK 4096
#define EMBD 1024
#define NEXP 8
#define HIDD 2048
#define NPAIR (NTOK * 2)

typedef __attribute__((ext_vector_type(8))) __bf16 bf16x8;
typedef __attribute__((ext_vector_type(4))) float f32x4;

union V16 { uint4 u; bf16x8 b; };

__device__ __forceinline__ uint16_t f2bf(float f) {
    uint32_t u = __float_as_uint(f);
    return (uint16_t)((u + 0x7FFFu + ((u >> 16) & 1u)) >> 16);
}
__device__ __forceinline__ float bf2f(uint16_t u) {
    return __uint_as_float(((uint32_t)u) << 16);
}
__device__ __forceinline__ void gl_lds16(const uint16_t* g, uint16_t* l) {
    __builtin_amdgcn_global_load_lds(
        (const __attribute__((address_space(1))) void*)g,
        (__attribute__((address_space(3))) void*)l, 16, 0, 0);
}

// ---- fused transpose-cast of all 3 weight tensors in ONE dispatch ----
// src [E][K][N] fp32 -> dst [E][N][K] bf16, 64x64 tiles, 16B loads + 16B stores
#define W1_TILES 4096   // (2048/64)*(1024/64)*8
#define WG_TILES 8192   // (2048/64)*(2048/64)*8
#define W2_TILES 4096   // (1024/64)*(2048/64)*8
__global__ __launch_bounds__(256) void transcast3_kernel(
    const float* __restrict__ W1, const float* __restrict__ Wg,
    const float* __restrict__ W2, uint16_t* __restrict__ W1t,
    uint16_t* __restrict__ Wgt, uint16_t* __restrict__ W2t) {
    int id = blockIdx.x;
    const float* src; uint16_t* dst; int K, N;
    if (id < W1_TILES) { src = W1; dst = W1t; K = EMBD; N = HIDD; }
    else if (id < W1_TILES + WG_TILES) { id -= W1_TILES; src = Wg; dst = Wgt; K = HIDD; N = HIDD; }
    else { id -= W1_TILES + WG_TILES; src = W2; dst = W2t; K = HIDD; N = EMBD; }
    int tn = N >> 6, tk = K >> 6;
    int per_e = tn * tk;           // power of two
    int e = id / per_e, r = id % per_e;
    int n0 = (r % tn) * 64, k0 = (r / tn) * 64;

    __shared__ uint16_t tile[64][68];
    const float* S = src + ((size_t)e * K + k0) * N + n0;
    uint16_t* D = dst + ((size_t)e * N + n0) * K + k0;
    int t = threadIdx.x;
    int rn = (t & 15) * 4, rk = t >> 4;
#pragma unroll
    for (int p = 0; p < 4; p++) {
        int k = rk + p * 16;
        float4 v = *(const float4*)(S + (size_t)k * N + rn);
        ushort4 o;
        o.x = f2bf(v.x); o.y = f2bf(v.y); o.z = f2bf(v.z); o.w = f2bf(v.w);
        *(ushort4*)&tile[k][rn] = o;
    }
    __syncthreads();
    int wn = t >> 3, wk = (t & 7) * 8;
#pragma unroll
    for (int p = 0; p < 2; p++) {
        int n = wn + p * 32;
        uint32_t w0 = (uint32_t)tile[wk + 0][n] | ((uint32_t)tile[wk + 1][n] << 16);
        uint32_t w1 = (uint32_t)tile[wk + 2][n] | ((uint32_t)tile[wk + 3][n] << 16);
        uint32_t w2 = (uint32_t)tile[wk + 4][n] | ((uint32_t)tile[wk + 5][n] << 16);
        uint32_t w3 = (uint32_t)tile[wk + 6][n] | ((uint32_t)tile[wk + 7][n] << 16);
        uint4 pk = {w0, w1, w2, w3};
        *(uint4*)(D + (size_t)n * K + wk) = pk;
    }
}

// ---- router (+ x cast fused): one wave per token ----
__global__ __launch_bounds__(64) void router_kernel(const float* __restrict__ x,
                                                    const float* __restrict__ Wr,
                                                    const float* __restrict__ br,
                                                    uint16_t* __restrict__ xb,
                                                    int* __restrict__ counts,
                                                    int* __restrict__ pair_e,
                                                    float* __restrict__ pair_p) {
    int tok = blockIdx.x;
    int lane = threadIdx.x;
    const float* xr = x + (size_t)tok * EMBD;
    uint16_t* xbr = xb + (size_t)tok * EMBD;
    float acc[NEXP];
#pragma unroll
    for (int e = 0; e < NEXP; e++) acc[e] = 0.f;
    for (int d = lane; d < EMBD; d += 64) {
        float xv = xr[d];
        xbr[d] = f2bf(xv);
#pragma unroll
        for (int e = 0; e < NEXP; e++) acc[e] += xv * Wr[d * NEXP + e];
    }
#pragma unroll
    for (int e = 0; e < NEXP; e++) {
#pragma unroll
        for (int off = 32; off > 0; off >>= 1)
            acc[e] += __shfl_down(acc[e], off, 64);
    }
    if (lane == 0) {
        float lg[NEXP];
#pragma unroll
        for (int e = 0; e < NEXP; e++) lg[e] = acc[e] + br[e];
        int e0 = 0;
#pragma unroll
        for (int e = 1; e < NEXP; e++) if (lg[e] > lg[e0]) e0 = e;
        int e1 = (e0 == 0) ? 1 : 0;
#pragma unroll
        for (int e = 0; e < NEXP; e++) if (e != e0 && lg[e] > lg[e1]) e1 = e;
        float mx = lg[0];
#pragma unroll
        for (int e = 1; e < NEXP; e++) mx = fmaxf(mx, lg[e]);
        float s = 0.f, p[NEXP];
#pragma unroll
        for (int e = 0; e < NEXP; e++) { p[e] = __expf(lg[e] - mx); s += p[e]; }
        float inv = 1.f / s;
        pair_e[tok * 2 + 0] = e0; pair_p[tok * 2 + 0] = p[e0] * inv;
        pair_e[tok * 2 + 1] = e1; pair_p[tok * 2 + 1] = p[e1] * inv;
        atomicAdd(&counts[e0], 1);
        atomicAdd(&counts[e1], 1);
    }
}

// ---- scatter (computes offsets locally from counts) ----
__global__ __launch_bounds__(256) void scatter_kernel(const int* __restrict__ pair_e,
                                                      const int* __restrict__ counts,
                                                      int* __restrict__ cursors,
                                                      int* __restrict__ toklist,
                                                      int* __restrict__ posmap) {
    int i = blockIdx.x * 256 + threadIdx.x;  // pair index
    int e = pair_e[i];
    int offs = 0;
    for (int j = 0; j < NEXP; j++) offs += (j < e) ? counts[j] : 0;
    int pos = offs + atomicAdd(&cursors[e], 1);
    toklist[pos] = i >> 1;
    posmap[i] = pos;
}

// ---- grouped GEMM, m97 structure: 128x128 tile, BK=32, 4 waves, 4x4 MFMA/wave
template <int KDIM, int NDIM, bool GATHER_A, bool RELU>
__global__ __launch_bounds__(256) void gemm_kernel(
    const uint16_t* __restrict__ Abase, const uint16_t* __restrict__ Btbase,
    const float* __restrict__ bbase, uint16_t* __restrict__ Out,
    const int* __restrict__ counts, const int* __restrict__ toklist) {
    int e = blockIdx.z;
    int offs = 0;
    for (int j = 0; j < NEXP; j++) offs += (j < e) ? counts[j] : 0;
    int n_e = counts[e];
    int m0 = blockIdx.y * 128;
    if (m0 >= n_e) return;
    int n0 = blockIdx.x * 128;
    const uint16_t* Bt = Btbase + (size_t)e * NDIM * KDIM;

    // XOR swizzle: LDS slot s of row r holds global k-segment s ^ ((r>>1)&3)
    __shared__ uint16_t As[128 * 32];
    __shared__ uint16_t Bs[128 * 32];

    int tid = threadIdx.x;
    int lane = tid & 63;
    int wave = tid >> 6;

    int sr = tid >> 2;
    int ss = tid & 3;
    const uint16_t* arp[2];
    const uint16_t* brp[2];
#pragma unroll
    for (int p = 0; p < 2; p++) {
        int r = p * 64 + sr;
        int gs = ss ^ ((r >> 1) & 3);
        int grow;
        if (GATHER_A) {
            int idx = m0 + r;
            if (idx >= n_e) idx = 0;
            grow = toklist[offs + idx];
        } else {
            grow = offs + m0 + r;  // rows >= n_e read garbage; never stored
        }
        arp[p] = Abase + (size_t)grow * KDIM + gs * 8;
        brp[p] = Bt + (size_t)(n0 + r) * KDIM + gs * 8;
    }
    uint16_t* alds[2] = { &As[wave * 512], &As[2048 + wave * 512] };
    uint16_t* blds[2] = { &Bs[wave * 512], &Bs[2048 + wave * 512] };

    int wm = (wave >> 1) * 64;
    int wn = (wave & 1) * 64;
    int l16 = lane & 15, qd = lane >> 4;
    const uint16_t* afp[4];
    const uint16_t* bfp[4];
#pragma unroll
    for (int t = 0; t < 4; t++) {
        int ar = wm + t * 16 + l16;
        afp[t] = &As[ar * 32 + (qd ^ ((ar >> 1) & 3)) * 8];
        int br = wn + t * 16 + l16;
        bfp[t] = &Bs[br * 32 + (qd ^ ((br >> 1) & 3)) * 8];
    }

    f32x4 acc[4][4];
    f32x4 zero = {0.f, 0.f, 0.f, 0.f};
#pragma unroll
    for (int i = 0; i < 4; i++)
#pragma unroll
        for (int j = 0; j < 4; j++) acc[i][j] = zero;

    for (int kb = 0; kb < KDIM; kb += 32) {
#pragma unroll
        for (int p = 0; p < 2; p++) {
            gl_lds16(arp[p] + kb, alds[p]);
            gl_lds16(brp[p] + kb, blds[p]);
        }
        __syncthreads();
        V16 af[4], bf[4];
#pragma unroll
        for (int t = 0; t < 4; t++) {
            af[t].u = *(const uint4*)(afp[t]);
            bf[t].u = *(const uint4*)(bfp[t]);
        }
#pragma unroll
        for (int i = 0; i < 4; i++)
#pragma unroll
            for (int j = 0; j < 4; j++)
                acc[i][j] = __builtin_amdgcn_mfma_f32_16x16x32_bf16(
                    af[i].b, bf[j].b, acc[i][j], 0, 0, 0);
        __syncthreads();
    }

    // epilogue: C/D layout col=lane&15, row=(lane>>4)*4+reg
    const float* bias = bbase + (size_t)e * NDIM;
    int mrem = n_e - m0;
#pragma unroll
    for (int i = 0; i < 4; i++) {
        int rb = wm + i * 16 + qd * 4;
#pragma unroll
        for (int j = 0; j < 4; j++) {
            int col = n0 + wn + j * 16 + l16;
            float bv = bias[col];
#pragma unroll
            for (int r = 0; r < 4; r++) {
                int lr = rb + r;
                if (lr < mrem) {
                    float v = acc[i][j][r] + bv;
                    if (RELU) v = fmaxf(v, 0.f);
                    Out[(size_t)(offs + m0 + lr) * NDIM + col] = f2bf(v);
                }
            }
        }
    }
}

// ---- combine: out[t] = p0*y[pos0] + p1*y[pos1] ----
__global__ __launch_bounds__(256) void combine_kernel(const uint16_t* __restrict__ y,
                                                      const int* __restrict__ posmap,
                                                      const float* __restrict__ pair_p,
                                                      float* __restrict__ out) {
    int t = blockIdx.x;
    int d4 = threadIdx.x;
    int p0 = posmap[t * 2], p1 = posmap[t * 2 + 1];
    float w0 = pair_p[t * 2], w1 = pair_p[t * 2 + 1];
    ushort4 a = ((const ushort4*)(y + (size_t)p0 * EMBD))[d4];
    ushort4 b = ((const ushort4*)(y + (size_t)p1 * EMBD))[d4];
    float4 o;
    o.x = w0 * bf2f(a.x) + w1 * bf2f(b.x);
    o.y = w0 * bf2f(a.y) + w1 * bf2f(b.y);
    o.z = w0 * bf2f(a.z) + w1 * bf2f(b.z);
    o.w = w0 * bf2f(a.w) + w1 * bf2f(b.w);
    ((float4*)(out + (size_t)t * EMBD))[d4] = o;
}

extern "C" void kernel_launch(void* const* d_in, const int* in_sizes, int n_in,
                              void* d_out, int out_size, void* d_ws, size_t ws_size,
                              hipStream_t stream) {
    const float* x  = (const float*)d_in[0];
    const float* Wr = (const float*)d_in[1];
    const float* br = (const float*)d_in[2];
    const float* W1 = (const float*)d_in[3];
    const float* b1 = (const float*)d_in[4];
    const float* Wg = (const float*)d_in[5];
    const float* bg = (const float*)d_in[6];
    const float* W2 = (const float*)d_in[7];
    const float* b2 = (const float*)d_in[8];
    float* out = (float*)d_out;

    char* ws = (char*)d_ws;
    uint16_t* xb  = (uint16_t*)ws;                    //  8 MB
    uint16_t* h   = (uint16_t*)(ws + (8ull << 20));   // 32 MB; y aliases (h dead at L3)
    uint16_t* yb  = h;
    uint16_t* W1t = (uint16_t*)(ws + (40ull << 20));  // 32 MB; g aliases (W1t dead at L2)
    uint16_t* g   = W1t;
    uint16_t* Wgt = (uint16_t*)(ws + (72ull << 20));  // 64 MB
    uint16_t* W2t = (uint16_t*)(ws + (136ull << 20)); // 32 MB
    int* meta = (int*)(ws + (168ull << 20));
    int*   counts  = meta;                    // 8
    int*   cursors = meta + 8;                // 8
    int*   pair_e  = meta + 16;               // NPAIR
    int*   toklist = meta + 16 + NPAIR;       // NPAIR
    int*   posmap  = meta + 16 + 2 * NPAIR;   // NPAIR
    float* pair_p  = (float*)(meta + 16 + 3 * NPAIR);  // NPAIR

    hipMemsetAsync(counts, 0, 16 * sizeof(int), stream);

    router_kernel<<<NTOK, 64, 0, stream>>>(x, Wr, br, xb, counts, pair_e, pair_p);
    transcast3_kernel<<<W1_TILES + WG_TILES + W2_TILES, 256, 0, stream>>>(
        W1, Wg, W2, W1t, Wgt, W2t);
    scatter_kernel<<<NPAIR / 256, 256, 0, stream>>>(pair_e, counts, cursors, toklist, posmap);

    // layer1: [n_e,1024] x [1024,2048]
    gemm_kernel<EMBD, HIDD, true, false>
        <<<dim3(HIDD / 128, NTOK / 128, NEXP), 256, 0, stream>>>(
            xb, W1t, b1, h, counts, toklist);
    // layer2: relu([n_e,2048] x [2048,2048])
    gemm_kernel<HIDD, HIDD, false, true>
        <<<dim3(HIDD / 128, NTOK / 128, NEXP), 256, 0, stream>>>(
            h, Wgt, bg, g, counts, toklist);
    // layer3: [n_e,2048] x [2048,1024]
    gemm_kernel<HIDD, EMBD, false, false>
        <<<dim3(EMBD / 128, NTOK / 128, NEXP), 256, 0, stream>>>(
            g, W2t, b2, yb, counts, toklist);
    combine_kernel<<<NTOK, 256, 0, stream>>>(yb, posmap, pair_p, out);
}